// Round 18
// baseline (446.982 us; speedup 1.0000x reference)
//
#include <hip/hip_runtime.h>

#define TW_STEP 0.09817477042468103f  // 2*pi/64

typedef __bf16 bf16x8 __attribute__((ext_vector_type(8)));
typedef __bf16 bf16x4 __attribute__((ext_vector_type(4)));
typedef __bf16 bf16x2 __attribute__((ext_vector_type(2)));
typedef float  f32x4  __attribute__((ext_vector_type(4)));

// ---------------- workspace layout (bytes) ----------------
static constexpr size_t SZ_P   = (size_t)4*32*64*64*64*2;   // 67108864  field P [B][C][X][Y][Z] bf16
static constexpr size_t SZ_A   = (size_t)4*32*8*64*64*8;    // region A: (free)
static constexpr size_t SZ_B2  = (size_t)4*32*8*16*64*8;    // region B2: T2 bf16-pairs / U1 bf16-pairs [b][kz][x][kyi][o]
static constexpr size_t SZ_XF  = (size_t)4*32*8*16*16*8;    // 2097152   Xf (also reused for bn partials)
static constexpr size_t OFF_P  = 0;
static constexpr size_t OFF_A  = OFF_P + SZ_P;
static constexpr size_t OFF_B2 = OFF_A + SZ_A;
static constexpr size_t OFF_XF = OFF_B2 + SZ_B2;
static constexpr size_t OFF_YF = OFF_XF + SZ_XF;
static constexpr size_t OFF_TW  = OFF_YF + SZ_XF;           // 64 float2
static constexpr size_t OFF_BNP = OFF_TW + 512;             // 4 layers * 64 floats
static constexpr size_t OFF_W1B = OFF_BNP + 1024;           // 128*32 bf16 = 8192 B
static constexpr size_t OFF_B1P = OFF_W1B + 8192;           // 128 floats = 512 B
static constexpr size_t OFF_WFZ = OFF_B1P + 512;            // fwd z-DFT twiddles hi/lo: 2048 bf16 = 4096 B
static constexpr size_t OFF_WZ  = OFF_WFZ + 4096;           // inv z-DFT twiddles hi/lo: 4096 bf16 = 8192 B
static constexpr size_t OFF_WY  = OFF_WZ + 8192;            // fwd y/x-DFT B-frags: 4096 bf16 = 8192 B

// ---------------- kernels ----------------

__global__ void k_twinit(float2* tw, __bf16* wfz, __bf16* wz, __bf16* wy) {
    int t = threadIdx.x;                          // 256
    if (t < 64) { float s, c; sincosf(TW_STEP * t, &s, &c); tw[t] = make_float2(c, s); }
    for (int e = t; e < 1024; e += 256) {
        int half = e >> 9, rem = e & 511, kg = rem >> 7, tt = (rem >> 3) & 15, j = e & 7;
        int z = half * 32 + kg * 8 + j, k = tt >> 1;
        float ang = TW_STEP * (float)((k * z) & 63);
        float val = (tt & 1) ? -sinf(ang) : cosf(ang);
        __bf16 hi = (__bf16)val;
        wfz[e] = hi;
        wfz[1024 + e] = (__bf16)(val - (float)hi);
    }
    // wz: row-major [z][32 t]; t=0 ->1, t=1 ->0, t=2k -> 2cos(kz), t=2k+1 -> -2sin(kz)
    for (int e = t; e < 2048; e += 256) {
        int z = e >> 5, tt = e & 31, k = tt >> 1;
        float ang = TW_STEP * (float)((k * z) & 63);
        float val;
        if (tt == 0) val = 1.f;
        else if (tt == 1) val = 0.f;
        else val = (tt & 1) ? (-2.f * sinf(ang)) : (2.f * cosf(ang));
        __bf16 hi = (__bf16)val;
        wz[e] = hi;
        wz[2048 + e] = (__bf16)(val - (float)hi);
    }
    // wy: B-frags for fwd 64->16 DFT. e = ((kc*2+nt)*2+hl)*512 + l*8 + j
    for (int e = t; e < 4096; e += 256) {
        int j = e & 7, l = (e >> 3) & 63, hl = (e >> 9) & 1, nt = (e >> 10) & 1, kc = (e >> 11) & 1;
        int f = l & 15;
        int F = f < 8 ? f : f + 48;
        int y = kc * 32 + ((l >> 4) & 3) * 8 + j;
        float ang = TW_STEP * (float)((F * y) & 63);
        float val = nt ? sinf(ang) : cosf(ang);
        __bf16 hi = (__bf16)val;
        wy[e] = hl ? (__bf16)(val - (float)hi) : hi;
    }
}

// lift: x[B,X,Y,Z,3] -> P[b][w][x][y][z] (bf16)
__global__ __launch_bounds__(256) void k_lift(const float* __restrict__ x,
                                              const float* __restrict__ w,
                                              const float* __restrict__ bias,
                                              __bf16* __restrict__ P) {
    int v = blockIdx.x * 256 + threadIdx.x;      // 1048576 voxels
    int z = v & 63, y = (v >> 6) & 63, xx = (v >> 12) & 63, b = v >> 18;
    float i0 = x[(size_t)v * 3 + 0], i1 = x[(size_t)v * 3 + 1], i2 = x[(size_t)v * 3 + 2];
#pragma unroll
    for (int c = 0; c < 32; c++) {
        float val = bias[c] + w[c * 3 + 0] * i0 + w[c * 3 + 1] * i1 + w[c * 3 + 2] * i2;
        P[(size_t)(((b * 32 + c) * 64 + xx) * 64 + y) * 64 + z] = (__bf16)val;
    }
}

// fused forward z-DFT + y-DFT via MFMA: P (bn+relu on the fly) -> T2 bf16-pairs
// [((b*32+c)*8+kz)*1024 + f*64 + x]. LDS: ddsh (4608 B) aliases into dead hs2buf (9216 B).
__global__ __launch_bounds__(256) void k_zfwd2(const __bf16* __restrict__ P,
                                               const __bf16* __restrict__ wfz,
                                               const __bf16* __restrict__ wy,
                                               const float* __restrict__ bnp, int relu,
                                               unsigned* __restrict__ T2u) {
    int blk = blockIdx.x;                         // 8192 = (b,c,x)
    int x = blk & 63, c = (blk >> 6) & 31, b = blk >> 11;
    __shared__ __bf16 hs2buf[64][72];             // 9216 B (phase A staging)
    __shared__ float ttmp[16][66];                // 4224 B
    __shared__ __bf16 af[16][72];                 // 2304 B
    float (*ddsh)[2][16][18] = (float(*)[2][16][18])hs2buf;  // 4608 B alias (phase C)
    int tid = threadIdx.x, l = tid & 63, w = tid >> 6;
    {
        int y = tid >> 2, q = tid & 3;
        float scb = 1.f, shb = 0.f;
        if (bnp) { scb = bnp[c]; shb = bnp[32 + c]; }
        const __bf16* src = P + ((size_t)((b * 32 + c) * 64 + x) * 64 + y) * 64 + q * 16;
        bf16x8 v0 = ((const bf16x8*)src)[0], v1 = ((const bf16x8*)src)[1];
        bf16x8 o0, o1;
#pragma unroll
        for (int j = 0; j < 8; j++) {
            float a = (float)v0[j], bb = (float)v1[j];
            if (bnp) {
                a = fmaf(a, scb, shb); bb = fmaf(bb, scb, shb);
                if (relu) { a = fmaxf(a, 0.f); bb = fmaxf(bb, 0.f); }
            }
            o0[j] = (__bf16)a; o1[j] = (__bf16)bb;
        }
        *(bf16x8*)&hs2buf[y][q * 16] = o0;
        *(bf16x8*)&hs2buf[y][q * 16 + 8] = o1;
    }
    __syncthreads();
    int col = l & 15, kg = l >> 4;
    {
        f32x4 acc = (f32x4){0.f, 0.f, 0.f, 0.f};
#pragma unroll
        for (int half = 0; half < 2; half++) {
            bf16x8 a = *(const bf16x8*)&hs2buf[w * 16 + col][half * 32 + kg * 8];
            const __bf16* wp = wfz + ((half * 4 + kg) * 16 + col) * 8;
            bf16x8 bh = *(const bf16x8*)wp;
            bf16x8 blo = *(const bf16x8*)(wp + 1024);
            acc = __builtin_amdgcn_mfma_f32_16x16x32_bf16(a, bh, acc, 0, 0, 0);
            acc = __builtin_amdgcn_mfma_f32_16x16x32_bf16(a, blo, acc, 0, 0, 0);
        }
#pragma unroll
        for (int r = 0; r < 4; r++) ttmp[col][w * 16 + kg * 4 + r] = acc[r];
    }
    __syncthreads();                              // hs2buf dead from here on
    {
        int row = tid >> 4, yq = tid & 15;
        float v0 = ttmp[row][yq * 4 + 0];
        float v1 = ttmp[row][yq * 4 + 1];
        float v2 = ttmp[row][yq * 4 + 2];
        float v3 = ttmp[row][yq * 4 + 3];
        bf16x4 o;
        o[0] = (__bf16)v0; o[1] = (__bf16)v1; o[2] = (__bf16)v2; o[3] = (__bf16)v3;
        *(bf16x4*)&af[row][yq * 4] = o;
    }
    __syncthreads();
    {
        int nt = w & 1, kc = w >> 1;
        bf16x8 a = *(const bf16x8*)&af[col][kc * 32 + kg * 8];
        const __bf16* wp = wy + (kc * 2 + nt) * 1024 + l * 8;
        bf16x8 bh = *(const bf16x8*)wp;
        bf16x8 blo = *(const bf16x8*)(wp + 512);
        f32x4 d = (f32x4){0.f, 0.f, 0.f, 0.f};
        d = __builtin_amdgcn_mfma_f32_16x16x32_bf16(a, bh, d, 0, 0, 0);
        d = __builtin_amdgcn_mfma_f32_16x16x32_bf16(a, blo, d, 0, 0, 0);
#pragma unroll
        for (int r = 0; r < 4; r++) ddsh[kc][nt][kg * 4 + r][col] = d[r];
    }
    __syncthreads();
    if (tid < 128) {
        int kz = tid >> 4, f = tid & 15;
        int tre = 2 * kz, tim = 2 * kz + 1;
        float Re = (ddsh[0][0][tre][f] + ddsh[1][0][tre][f])
                 + (ddsh[0][1][tim][f] + ddsh[1][1][tim][f]);
        float Im = (ddsh[0][0][tim][f] + ddsh[1][0][tim][f])
                 - (ddsh[0][1][tre][f] + ddsh[1][1][tre][f]);
        union { __bf16 h[2]; unsigned u; } pk;
        pk.h[0] = (__bf16)Re; pk.h[1] = (__bf16)Im;
        T2u[(size_t)((b * 32 + c) * 8 + kz) * 1024 + f * 64 + x] = pk.u;
    }
}

// MFMA 64->16 complex DFT (x-stage)
__global__ __launch_bounds__(256) void k_dftm(const __bf16* __restrict__ in,
                                              float2* __restrict__ outf,
                                              const __bf16* __restrict__ wy) {
    int rb = blockIdx.x * 16;
    __shared__ __bf16 af[32 * 72];                // 4608 B
    __shared__ float dd[2][2][16][18];            // 4608 B
    int tid = threadIdx.x, l = tid & 63, w = tid >> 6;
    {
        int r = tid >> 4, yq = tid & 15;
        bf16x8 v = *(const bf16x8*)(in + ((size_t)(rb + r) * 64 + yq * 4) * 2);
        bf16x4 re, im;
#pragma unroll
        for (int j = 0; j < 4; j++) { re[j] = v[2 * j]; im[j] = v[2 * j + 1]; }
        *(bf16x4*)&af[(2 * r) * 72 + yq * 4] = re;
        *(bf16x4*)&af[(2 * r + 1) * 72 + yq * 4] = im;
    }
    __syncthreads();
    int mt = w >> 1, nt = w & 1, col = l & 15, kg = l >> 4;
    f32x4 acc = (f32x4){0.f, 0.f, 0.f, 0.f};
#pragma unroll
    for (int kc = 0; kc < 2; kc++) {
        bf16x8 a = *(const bf16x8*)&af[(mt * 16 + col) * 72 + kc * 32 + kg * 8];
        const __bf16* wp = wy + (kc * 2 + nt) * 1024 + l * 8;
        bf16x8 bh = *(const bf16x8*)wp;
        bf16x8 blo = *(const bf16x8*)(wp + 512);
        acc = __builtin_amdgcn_mfma_f32_16x16x32_bf16(a, bh, acc, 0, 0, 0);
        acc = __builtin_amdgcn_mfma_f32_16x16x32_bf16(a, blo, acc, 0, 0, 0);
    }
#pragma unroll
    for (int r = 0; r < 4; r++) dd[mt][nt][kg * 4 + r][col] = acc[r];
    __syncthreads();
    {
        int cr = tid >> 4, f = tid & 15;
        int mt2 = cr >> 3, tre = (2 * cr) & 15, tim = (2 * cr + 1) & 15;
        float Re = dd[mt2][0][tre][f] + dd[mt2][1][tim][f];
        float Im = dd[mt2][0][tim][f] - dd[mt2][1][tre][f];
        int rg = rb + cr;
        outf[rg * 16 + f] = make_float2(Re, Im);
    }
}

// spectral multiply
__global__ __launch_bounds__(128) void k_specmul(const float2* __restrict__ Xf,
                                                 const float* __restrict__ swl,
                                                 float2* __restrict__ Yf) {
    int m = blockIdx.x;                           // 2048 = (kz,kyi,kxi)
    int kxi = m & 15, kyi = (m >> 4) & 15, kz = m >> 8;
    int corner = (kxi >= 8 ? 1 : 0) + (kyi >= 8 ? 2 : 0);
    int mx = kxi & 7, my = kyi & 7;
    __shared__ float2 wsd[1024];
    __shared__ float2 xfs[128];
    int tid = threadIdx.x;
    const float* wb = swl + (size_t)corner * 1048576 + mx * 128 + my * 16 + kz * 2;
    for (int idx = tid; idx < 1024; idx += 128) {
        int i = idx >> 5, o = idx & 31;
        const float* p = wb + (size_t)i * 32768 + o * 1024;
        wsd[idx] = make_float2(p[0], p[1]);
    }
    {
        int b = tid >> 5, i = tid & 31;
        xfs[tid] = Xf[(((b * 32 + i) * 8 + kz) * 16 + kyi) * 16 + kxi];
    }
    __syncthreads();
    int b = tid >> 5, o = tid & 31;
    float ar = 0.f, ai = 0.f;
#pragma unroll
    for (int i = 0; i < 32; i++) {
        float2 xv = xfs[b * 32 + i];
        float2 wv = wsd[i * 32 + o];
        ar += xv.x * wv.x - xv.y * wv.y;
        ai += xv.x * wv.y + xv.y * wv.x;
    }
    const float s = 1.0f / 262144.0f;
    Yf[(((b * 32 + o) * 8 + kz) * 16 + kyi) * 16 + kxi] = make_float2(ar * s, ai * s);
}

// inverse x: U1b[b][kz][x][kyi][o] (bf16 pairs) = sum_kx Yf * e^{+i}
__global__ __launch_bounds__(256) void k_xinv(const float2* __restrict__ Yf,
                                              unsigned* __restrict__ U1p) {
    int blk = blockIdx.x;                         // 1024 = (b,o,kz)
    int kz = blk & 7, o = (blk >> 3) & 31, b = blk >> 8;
    __shared__ float2 yfs[16][17];
    __shared__ float2 tw[64];
    int tid = threadIdx.x;
    if (tid < 64) { float s, c; sincosf(TW_STEP * tid, &s, &c); tw[tid] = make_float2(c, s); }
    {
        int kyi = tid >> 4, kxi = tid & 15;
        yfs[kyi][kxi] = Yf[(size_t)((b * 32 + o) * 8 + kz) * 256 + tid];
    }
    __syncthreads();
    size_t base = (size_t)((b * 8 + kz) * 64) * 512 + o;
#pragma unroll
    for (int r = 0; r < 4; r++) {
        int idx = tid + r * 256;
        int x = idx >> 4, kyi = idx & 15;
        float ar = 0.f, ai = 0.f;
#pragma unroll
        for (int kxi = 0; kxi < 16; kxi++) {
            int f = kxi < 8 ? kxi : kxi + 48;
            float2 t = tw[(f * x) & 63];
            float2 v = yfs[kyi][kxi];
            ar += v.x * t.x - v.y * t.y;
            ai += v.x * t.y + v.y * t.x;
        }
        union { __bf16 h[2]; unsigned u; } pk;
        pk.h[0] = (__bf16)ar; pk.h[1] = (__bf16)ai;
        U1p[base + (size_t)x * 512 + kyi * 32] = pk.u;
    }
}

// fused: P <- irfft_z(yinv(U1b)) + MFMA-pointwise(h) + cb ; bn partials out.
// 512 threads: wave w -> (w2 = w>>2 channel half, wy = w&3 y-row). Per-thread work halved.
__global__ __launch_bounds__(512) void k_fuse(__bf16* __restrict__ P,
                                              const unsigned* __restrict__ U1p,
                                              const float* __restrict__ cwl,
                                              const float* __restrict__ cbl,
                                              const __bf16* __restrict__ wz,
                                              const float* __restrict__ bnp, int relu,
                                              float* __restrict__ part) {
    int blk = blockIdx.x;                         // 4096 = (yt,b,x)
    int yt = blk >> 8, bxi = blk & 255;
    int b = bxi >> 6, x = bxi & 63;
    int y0 = yt * 4;
    __shared__ __bf16 hs[256 * 40];               // 20480 B
    __shared__ __bf16 u2b[4][32][20];             // 5120 B
    __shared__ float2 twl[64];                    // 512 B
    __shared__ float sredS[8][16], sredQ[8][16];  // 1024 B
    int tid = threadIdx.x;
    int l = tid & 63, w = tid >> 6;               // 8 waves
    if (tid < 64) { float s, c; sincosf(TW_STEP * tid, &s, &c); twl[tid] = make_float2(c, s); }
    __syncthreads();

    int col = l & 15, kg = l >> 4;
    int w2 = w >> 2, wy = w & 3;                  // channel half, y row
    // cw fragment for this wave's half: cw[o][c], o = w2*16+col, c = kg*8+j
    bf16x8 cwf;
    float cbv;
    {
        int o = w2 * 16 + col;
        const float4* p4 = (const float4*)(cwl + o * 32 + kg * 8);
        float4 q0 = p4[0], q1 = p4[1];
        cwf[0] = (__bf16)q0.x; cwf[1] = (__bf16)q0.y;
        cwf[2] = (__bf16)q0.z; cwf[3] = (__bf16)q0.w;
        cwf[4] = (__bf16)q1.x; cwf[5] = (__bf16)q1.y;
        cwf[6] = (__bf16)q1.z; cwf[7] = (__bf16)q1.w;
        cbv = cbl[o];
    }

    // stage hs (bn+relu applied); jj-rotation. thread (c = tid>>4, yh = (tid>>3)&1, j = tid&7)
    {
        int c = tid >> 4, yh = (tid >> 3) & 1, j = tid & 7;
        float scb = 1.f, shb = 0.f;
        if (bnp) { scb = bnp[c]; shb = bnp[32 + c]; }
        const __bf16* src = P + ((size_t)((b * 32 + c) * 64 + x) * 64 + y0) * 64 + j * 8;
#pragma unroll
        for (int qq = 0; qq < 2; qq++) {
            int q = yh * 2 + qq;
            bf16x8 v8 = *(const bf16x8*)(src + q * 64);
            float fv[8];
#pragma unroll
            for (int jj = 0; jj < 8; jj++) {
                float v = (float)v8[jj];
                if (bnp) { v = fmaf(v, scb, shb); if (relu) v = fmaxf(v, 0.f); }
                fv[jj] = v;
            }
#pragma unroll
            for (int s = 0; s < 8; s++) {
                int jr = (s + j) & 7;
                hs[(q * 64 + j * 8 + jr) * 40 + c] = (__bf16)fv[jr];
            }
        }
    }
    // stage u2b via y-inverse (conjugate-pair symmetric); thread (o, kz, half -> 2 yy)
    {
        int o = tid & 31, kz = (tid >> 5) & 7, half = tid >> 8;
        const unsigned* u1p = U1p + (size_t)((b * 8 + kz) * 64 + x) * 512 + o;
        float ur[16], ui[16];
#pragma unroll
        for (int kyi = 0; kyi < 16; kyi++) {
            union { unsigned u; __bf16 h[2]; } pk;
            pk.u = u1p[kyi * 32];
            ur[kyi] = (float)pk.h[0]; ui[kyi] = (float)pk.h[1];
        }
        float spr[8], sdr[8], spi[8], sdi[8];
#pragma unroll
        for (int p = 1; p < 8; p++) {
            spr[p] = ur[p] + ur[16 - p]; sdr[p] = ur[p] - ur[16 - p];
            spi[p] = ui[p] + ui[16 - p]; sdi[p] = ui[p] - ui[16 - p];
        }
#pragma unroll
        for (int yq = 0; yq < 2; yq++) {
            int yy = half * 2 + yq;
            int y = y0 + yy;
            float arv = ur[0], aiv = ui[0];
            float2 t8 = twl[(8 * y) & 63];
            arv = fmaf(ur[8], t8.x, arv); arv = fmaf(ui[8], t8.y, arv);
            aiv = fmaf(ui[8], t8.x, aiv); aiv = fmaf(-ur[8], t8.y, aiv);
#pragma unroll
            for (int p = 1; p < 8; p++) {
                float2 t = twl[(p * y) & 63];
                arv = fmaf(spr[p], t.x, arv); arv = fmaf(-sdi[p], t.y, arv);
                aiv = fmaf(spi[p], t.x, aiv); aiv = fmaf(sdr[p], t.y, aiv);
            }
            union { __bf16 h[2]; unsigned u; } pk;
            pk.h[0] = (__bf16)arv; pk.h[1] = (__bf16)aiv;
            *(unsigned*)&u2b[yy][o][2 * kz] = pk.u;
        }
    }
    __syncthreads();

    // MFMA pointwise: wave (w2,wy): 4 M-tiles of z for y row wy, channel half w2
    f32x4 acc[4];
#pragma unroll
    for (int i = 0; i < 4; i++) {
        bf16x8 a = *(const bf16x8*)&hs[((wy * 4 + i) * 16 + col) * 40 + kg * 8];
        acc[i] = (f32x4){0.f, 0.f, 0.f, 0.f};
        acc[i] = __builtin_amdgcn_mfma_f32_16x16x32_bf16(a, cwf, acc[i], 0, 0, 0);
    }
    // MFMA irfft-z
    {
        bf16x8 u2f = (bf16x8){(__bf16)0.f, (__bf16)0.f, (__bf16)0.f, (__bf16)0.f,
                              (__bf16)0.f, (__bf16)0.f, (__bf16)0.f, (__bf16)0.f};
        if (kg < 2) {
            bf16x4 lo = *(const bf16x4*)&u2b[wy][w2 * 16 + col][kg * 8];
            bf16x4 hi = *(const bf16x4*)&u2b[wy][w2 * 16 + col][kg * 8 + 4];
            u2f[0] = lo[0]; u2f[1] = lo[1]; u2f[2] = lo[2]; u2f[3] = lo[3];
            u2f[4] = hi[0]; u2f[5] = hi[1]; u2f[6] = hi[2]; u2f[7] = hi[3];
        }
#pragma unroll
        for (int i = 0; i < 4; i++) {
            int z = i * 16 + col;
            const __bf16* wp = wz + z * 32 + kg * 8;
            bf16x8 wzh = *(const bf16x8*)wp;
            bf16x8 wzl = *(const bf16x8*)(wp + 2048);
            acc[i] = __builtin_amdgcn_mfma_f32_16x16x32_bf16(wzh, u2f, acc[i], 0, 0, 0);
            acc[i] = __builtin_amdgcn_mfma_f32_16x16x32_bf16(wzl, u2f, acc[i], 0, 0, 0);
        }
    }

    // store + stats
    float sacc = 0.f, ssacc = 0.f;
    {
        int o = w2 * 16 + col;
        __bf16* dstb = P + ((size_t)((b * 32 + o) * 64 + x) * 64 + (y0 + wy)) * 64;
#pragma unroll
        for (int i = 0; i < 4; i++) {
            int z0s = i * 16 + kg * 4;
            bf16x4 outv;
#pragma unroll
            for (int r = 0; r < 4; r++) {
                float f = acc[i][r] + cbv;
                sacc += f;
                ssacc = fmaf(f, f, ssacc);
                outv[r] = (__bf16)f;
            }
            *(bf16x4*)(dstb + z0s) = outv;
        }
    }
    sacc += __shfl_xor(sacc, 16, 64);
    sacc += __shfl_xor(sacc, 32, 64);
    ssacc += __shfl_xor(ssacc, 16, 64);
    ssacc += __shfl_xor(ssacc, 32, 64);
    if (l < 16) { sredS[w][col] = sacc; sredQ[w][col] = ssacc; }
    __syncthreads();
    if (tid < 32) {
        int ch2 = tid >> 4, chc = tid & 15;       // channel = ch2*16+chc
        float S = 0.f, SS = 0.f;
#pragma unroll
        for (int q = 0; q < 4; q++) {
            S += sredS[ch2 * 4 + q][chc];
            SS += sredQ[ch2 * 4 + q][chc];
        }
        part[((size_t)tid * 4096 + blk) * 2 + 0] = S;
        part[((size_t)tid * 4096 + blk) * 2 + 1] = SS;
    }
}

// one block per channel: reduce 4096 partials -> bn scale/shift
__global__ __launch_bounds__(256) void k_red2(const float* __restrict__ part,
                                              const float* __restrict__ gamma,
                                              const float* __restrict__ beta,
                                              float* __restrict__ bnp) {
    int c = blockIdx.x;
    int tid = threadIdx.x;
    const float2* pc = (const float2*)(part + (size_t)c * 8192);
    float s = 0.f, ss = 0.f;
#pragma unroll
    for (int q = 0; q < 16; q++) { float2 v = pc[tid * 16 + q]; s += v.x; ss += v.y; }
#pragma unroll
    for (int d = 32; d; d >>= 1) { s += __shfl_down(s, d, 64); ss += __shfl_down(ss, d, 64); }
    __shared__ float ws[8];
    if ((tid & 63) == 0) { ws[(tid >> 6) * 2] = s; ws[(tid >> 6) * 2 + 1] = ss; }
    __syncthreads();
    if (tid == 0) {
        double S = (double)ws[0] + ws[2] + ws[4] + ws[6];
        double SS = (double)ws[1] + ws[3] + ws[5] + ws[7];
        const double invN = 1.0 / 1048576.0;
        double mean = S * invN;
        double var = SS * invN - mean * mean;
        float scl = gamma[c] * rsqrtf((float)var + 1e-5f);
        bnp[c] = scl;
        bnp[32 + c] = beta[c] - (float)mean * scl;
    }
}

// fold final bn into fc1
__global__ void k_prep(const float* __restrict__ w1, const float* __restrict__ b1,
                       const float* __restrict__ bnp,
                       __bf16* __restrict__ w1b, float* __restrict__ b1p) {
    int f = threadIdx.x;
    if (f >= 128) return;
    float acc = b1[f];
#pragma unroll
    for (int c = 0; c < 32; c++) {
        float wv = w1[f * 32 + c];
        w1b[f * 32 + c] = (__bf16)(wv * bnp[c]);
        acc = fmaf(wv, bnp[32 + c], acc);
    }
    b1p[f] = acc;
}

// head: fc1 (bn pre-folded, MFMA, D[f][vox]) + relu -> fc2 (row-reduce, 2 shfl).
__global__ __launch_bounds__(256) void k_head(const __bf16* __restrict__ P,
                                              const __bf16* __restrict__ w1b,
                                              const float* __restrict__ b1p,
                                              const float* __restrict__ w2,
                                              const float* __restrict__ b2,
                                              float* __restrict__ out) {
    __shared__ __bf16 hs[64 * 40];                // [vox][ch], stride 40
    int tid = threadIdx.x;
    int b = blockIdx.x >> 9;                      // 512 blocks per batch
    int r0 = (blockIdx.x & 511) * 512;            // 512 voxels per block
    int l = tid & 63;
    int w = tid >> 6;
    int col = l & 15, kg = l >> 4, hi = l >> 4;

    bf16x8 afr[8];
    f32x4 b1q[8], w2q[8];
    {
#pragma unroll
        for (int nt = 0; nt < 8; nt++) {
            afr[nt] = *(const bf16x8*)(w1b + (nt * 16 + col) * 32 + kg * 8);
            b1q[nt] = ((const f32x4*)b1p)[nt * 4 + hi];
            w2q[nt] = ((const f32x4*)w2)[nt * 4 + hi];
        }
    }
    float b2v = b2[0];
    int sc_c = tid & 31, sc_j = tid >> 5;
    const __bf16* srcb = P + (size_t)(b * 32 + sc_c) * 262144 + r0 + sc_j * 8;

    for (int t = 0; t < 8; t++) {
        {
            bf16x8 v8 = *(const bf16x8*)(srcb + t * 64);
#pragma unroll
            for (int s = 0; s < 8; s++) {
                int jr = (s + sc_j * 4) & 7;
                hs[(sc_j * 8 + jr) * 40 + sc_c] = v8[jr];
            }
        }
        __syncthreads();
        bf16x8 hfr = *(const bf16x8*)&hs[(w * 16 + col) * 40 + kg * 8];
        f32x4 acc[8];
#pragma unroll
        for (int nt = 0; nt < 8; nt++) {
            acc[nt] = (f32x4){0.f, 0.f, 0.f, 0.f};
            acc[nt] = __builtin_amdgcn_mfma_f32_16x16x32_bf16(afr[nt], hfr, acc[nt], 0, 0, 0);
        }
        float s = 0.f;
#pragma unroll
        for (int nt = 0; nt < 8; nt++) {
#pragma unroll
            for (int r = 0; r < 4; r++) {
                float val = fmaxf(acc[nt][r] + b1q[nt][r], 0.f);
                s = fmaf(w2q[nt][r], val, s);
            }
        }
        s += __shfl_xor(s, 16, 64);
        s += __shfl_xor(s, 32, 64);
        if (l < 16)
            out[b * 262144 + r0 + t * 64 + w * 16 + l] = s + b2v;
        __syncthreads();
    }
}

// ---------------- launcher ----------------
extern "C" void kernel_launch(void* const* d_in, const int* in_sizes, int n_in,
                              void* d_out, int out_size, void* d_ws, size_t ws_size,
                              hipStream_t stream) {
    const float* x     = (const float*)d_in[0];
    const float* fc0_w = (const float*)d_in[1];
    const float* fc0_b = (const float*)d_in[2];
    const float* sw    = (const float*)d_in[3];
    const float* cw    = (const float*)d_in[4];
    const float* cb    = (const float*)d_in[5];
    const float* gamma = (const float*)d_in[6];
    const float* beta  = (const float*)d_in[7];
    const float* fc1_w = (const float*)d_in[8];
    const float* fc1_b = (const float*)d_in[9];
    const float* fc2_w = (const float*)d_in[10];
    const float* fc2_b = (const float*)d_in[11];

    char* ws = (char*)d_ws;
    __bf16* P    = (__bf16*)(ws + OFF_P);
    __bf16* T2b  = (__bf16*)(ws + OFF_B2);
    unsigned* T2u = (unsigned*)(ws + OFF_B2);
    unsigned* U1p = (unsigned*)(ws + OFF_B2);
    float2* Xf   = (float2*)(ws + OFF_XF);
    float2* Yf   = (float2*)(ws + OFF_YF);
    float*  part = (float*)(ws + OFF_XF);
    float2* gtw  = (float2*)(ws + OFF_TW);
    float*  bnp  = (float*)(ws + OFF_BNP);
    __bf16* w1b  = (__bf16*)(ws + OFF_W1B);
    float*  b1p  = (float*)(ws + OFF_B1P);
    __bf16* wfz  = (__bf16*)(ws + OFF_WFZ);
    __bf16* wz   = (__bf16*)(ws + OFF_WZ);
    __bf16* wy   = (__bf16*)(ws + OFF_WY);

    k_twinit<<<1, 256, 0, stream>>>(gtw, wfz, wz, wy);
    k_lift<<<4096, 256, 0, stream>>>(x, fc0_w, fc0_b, P);

    for (int i = 0; i < 4; i++) {
        const float* bprev = (i == 0) ? nullptr : (bnp + (i - 1) * 64);
        int relu = (i > 0) ? 1 : 0;
        k_zfwd2<<<8192, 256, 0, stream>>>(P, wfz, wy, bprev, relu, T2u);
        k_dftm<<<1024, 256, 0, stream>>>(T2b, Xf, wy);
        k_specmul<<<2048, 128, 0, stream>>>(Xf, sw + (size_t)i * 4194304, Yf);
        k_xinv<<<1024, 256, 0, stream>>>(Yf, U1p);
        k_fuse<<<4096, 512, 0, stream>>>(P, U1p, cw + i * 1024, cb + i * 32, wz, bprev, relu, part);
        k_red2<<<32, 256, 0, stream>>>(part, gamma + i * 32, beta + i * 32, bnp + i * 64);
    }

    k_prep<<<1, 128, 0, stream>>>(fc1_w, fc1_b, bnp + 3 * 64, w1b, b1p);
    k_head<<<2048, 256, 0, stream>>>(P, w1b, b1p, fc2_w, fc2_b, (float*)d_out);
}

// Round 19
// 417.650 us; speedup vs baseline: 1.0702x; 1.0702x over previous
//
#include <hip/hip_runtime.h>

#define TW_STEP 0.09817477042468103f  // 2*pi/64

typedef __bf16 bf16x8 __attribute__((ext_vector_type(8)));
typedef __bf16 bf16x4 __attribute__((ext_vector_type(4)));
typedef __bf16 bf16x2 __attribute__((ext_vector_type(2)));
typedef float  f32x4  __attribute__((ext_vector_type(4)));

// ---------------- workspace layout (bytes) ----------------
static constexpr size_t SZ_P   = (size_t)4*32*64*64*64*2;   // 67108864  field P [B][C][X][Y][Z] bf16
static constexpr size_t SZ_A   = (size_t)4*32*8*64*64*8;    // region A: (free)
static constexpr size_t SZ_B2  = (size_t)4*32*8*16*64*8;    // region B2: T2 bf16-pairs / U1 bf16-pairs [b][kz][x][kyi][o]
static constexpr size_t SZ_XF  = (size_t)4*32*8*16*16*8;    // 2097152   Xf (also reused for bn partials)
static constexpr size_t OFF_P  = 0;
static constexpr size_t OFF_A  = OFF_P + SZ_P;
static constexpr size_t OFF_B2 = OFF_A + SZ_A;
static constexpr size_t OFF_XF = OFF_B2 + SZ_B2;
static constexpr size_t OFF_YF = OFF_XF + SZ_XF;
static constexpr size_t OFF_TW  = OFF_YF + SZ_XF;           // 64 float2
static constexpr size_t OFF_BNP = OFF_TW + 512;             // 4 layers * 64 floats
static constexpr size_t OFF_W1B = OFF_BNP + 1024;           // 128*32 bf16 = 8192 B
static constexpr size_t OFF_B1P = OFF_W1B + 8192;           // 128 floats = 512 B
static constexpr size_t OFF_WFZ = OFF_B1P + 512;            // fwd z-DFT twiddles hi/lo: 2048 bf16 = 4096 B
static constexpr size_t OFF_WZ  = OFF_WFZ + 4096;           // inv z-DFT twiddles hi/lo: 4096 bf16 = 8192 B
static constexpr size_t OFF_WY  = OFF_WZ + 8192;            // fwd y/x-DFT B-frags: 4096 bf16 = 8192 B

// ---------------- kernels ----------------

__global__ void k_twinit(float2* tw, __bf16* wfz, __bf16* wz, __bf16* wy) {
    int t = threadIdx.x;                          // 256
    if (t < 64) { float s, c; sincosf(TW_STEP * t, &s, &c); tw[t] = make_float2(c, s); }
    for (int e = t; e < 1024; e += 256) {
        int half = e >> 9, rem = e & 511, kg = rem >> 7, tt = (rem >> 3) & 15, j = e & 7;
        int z = half * 32 + kg * 8 + j, k = tt >> 1;
        float ang = TW_STEP * (float)((k * z) & 63);
        float val = (tt & 1) ? -sinf(ang) : cosf(ang);
        __bf16 hi = (__bf16)val;
        wfz[e] = hi;
        wfz[1024 + e] = (__bf16)(val - (float)hi);
    }
    // wz: row-major [z][32 t]; t=0 ->1, t=1 ->0, t=2k -> 2cos(kz), t=2k+1 -> -2sin(kz)
    for (int e = t; e < 2048; e += 256) {
        int z = e >> 5, tt = e & 31, k = tt >> 1;
        float ang = TW_STEP * (float)((k * z) & 63);
        float val;
        if (tt == 0) val = 1.f;
        else if (tt == 1) val = 0.f;
        else val = (tt & 1) ? (-2.f * sinf(ang)) : (2.f * cosf(ang));
        __bf16 hi = (__bf16)val;
        wz[e] = hi;
        wz[2048 + e] = (__bf16)(val - (float)hi);
    }
    // wy: B-frags for fwd 64->16 DFT. e = ((kc*2+nt)*2+hl)*512 + l*8 + j
    for (int e = t; e < 4096; e += 256) {
        int j = e & 7, l = (e >> 3) & 63, hl = (e >> 9) & 1, nt = (e >> 10) & 1, kc = (e >> 11) & 1;
        int f = l & 15;
        int F = f < 8 ? f : f + 48;
        int y = kc * 32 + ((l >> 4) & 3) * 8 + j;
        float ang = TW_STEP * (float)((F * y) & 63);
        float val = nt ? sinf(ang) : cosf(ang);
        __bf16 hi = (__bf16)val;
        wy[e] = hl ? (__bf16)(val - (float)hi) : hi;
    }
}

// lift: x[B,X,Y,Z,3] -> P[b][w][x][y][z] (bf16)
__global__ __launch_bounds__(256) void k_lift(const float* __restrict__ x,
                                              const float* __restrict__ w,
                                              const float* __restrict__ bias,
                                              __bf16* __restrict__ P) {
    int v = blockIdx.x * 256 + threadIdx.x;      // 1048576 voxels
    int z = v & 63, y = (v >> 6) & 63, xx = (v >> 12) & 63, b = v >> 18;
    float i0 = x[(size_t)v * 3 + 0], i1 = x[(size_t)v * 3 + 1], i2 = x[(size_t)v * 3 + 2];
#pragma unroll
    for (int c = 0; c < 32; c++) {
        float val = bias[c] + w[c * 3 + 0] * i0 + w[c * 3 + 1] * i1 + w[c * 3 + 2] * i2;
        P[(size_t)(((b * 32 + c) * 64 + xx) * 64 + y) * 64 + z] = (__bf16)val;
    }
}

// fused forward z-DFT + y-DFT via MFMA: P (bn+relu on the fly) -> T2 bf16-pairs
// [((b*32+c)*8+kz)*1024 + f*64 + x]. LDS: ddsh (4608 B) aliases into dead hs2buf (9216 B).
__global__ __launch_bounds__(256) void k_zfwd2(const __bf16* __restrict__ P,
                                               const __bf16* __restrict__ wfz,
                                               const __bf16* __restrict__ wy,
                                               const float* __restrict__ bnp, int relu,
                                               unsigned* __restrict__ T2u) {
    int blk = blockIdx.x;                         // 8192 = (b,c,x)
    int x = blk & 63, c = (blk >> 6) & 31, b = blk >> 11;
    __shared__ __bf16 hs2buf[64][72];             // 9216 B (phase A staging)
    __shared__ float ttmp[16][66];                // 4224 B
    __shared__ __bf16 af[16][72];                 // 2304 B
    float (*ddsh)[2][16][18] = (float(*)[2][16][18])hs2buf;  // 4608 B alias (phase C)
    int tid = threadIdx.x, l = tid & 63, w = tid >> 6;
    {
        int y = tid >> 2, q = tid & 3;
        float scb = 1.f, shb = 0.f;
        if (bnp) { scb = bnp[c]; shb = bnp[32 + c]; }
        const __bf16* src = P + ((size_t)((b * 32 + c) * 64 + x) * 64 + y) * 64 + q * 16;
        bf16x8 v0 = ((const bf16x8*)src)[0], v1 = ((const bf16x8*)src)[1];
        bf16x8 o0, o1;
#pragma unroll
        for (int j = 0; j < 8; j++) {
            float a = (float)v0[j], bb = (float)v1[j];
            if (bnp) {
                a = fmaf(a, scb, shb); bb = fmaf(bb, scb, shb);
                if (relu) { a = fmaxf(a, 0.f); bb = fmaxf(bb, 0.f); }
            }
            o0[j] = (__bf16)a; o1[j] = (__bf16)bb;
        }
        *(bf16x8*)&hs2buf[y][q * 16] = o0;
        *(bf16x8*)&hs2buf[y][q * 16 + 8] = o1;
    }
    __syncthreads();
    int col = l & 15, kg = l >> 4;
    {
        f32x4 acc = (f32x4){0.f, 0.f, 0.f, 0.f};
#pragma unroll
        for (int half = 0; half < 2; half++) {
            bf16x8 a = *(const bf16x8*)&hs2buf[w * 16 + col][half * 32 + kg * 8];
            const __bf16* wp = wfz + ((half * 4 + kg) * 16 + col) * 8;
            bf16x8 bh = *(const bf16x8*)wp;
            bf16x8 blo = *(const bf16x8*)(wp + 1024);
            acc = __builtin_amdgcn_mfma_f32_16x16x32_bf16(a, bh, acc, 0, 0, 0);
            acc = __builtin_amdgcn_mfma_f32_16x16x32_bf16(a, blo, acc, 0, 0, 0);
        }
#pragma unroll
        for (int r = 0; r < 4; r++) ttmp[col][w * 16 + kg * 4 + r] = acc[r];
    }
    __syncthreads();                              // hs2buf dead from here on
    {
        int row = tid >> 4, yq = tid & 15;
        float v0 = ttmp[row][yq * 4 + 0];
        float v1 = ttmp[row][yq * 4 + 1];
        float v2 = ttmp[row][yq * 4 + 2];
        float v3 = ttmp[row][yq * 4 + 3];
        bf16x4 o;
        o[0] = (__bf16)v0; o[1] = (__bf16)v1; o[2] = (__bf16)v2; o[3] = (__bf16)v3;
        *(bf16x4*)&af[row][yq * 4] = o;
    }
    __syncthreads();
    {
        int nt = w & 1, kc = w >> 1;
        bf16x8 a = *(const bf16x8*)&af[col][kc * 32 + kg * 8];
        const __bf16* wp = wy + (kc * 2 + nt) * 1024 + l * 8;
        bf16x8 bh = *(const bf16x8*)wp;
        bf16x8 blo = *(const bf16x8*)(wp + 512);
        f32x4 d = (f32x4){0.f, 0.f, 0.f, 0.f};
        d = __builtin_amdgcn_mfma_f32_16x16x32_bf16(a, bh, d, 0, 0, 0);
        d = __builtin_amdgcn_mfma_f32_16x16x32_bf16(a, blo, d, 0, 0, 0);
#pragma unroll
        for (int r = 0; r < 4; r++) ddsh[kc][nt][kg * 4 + r][col] = d[r];
    }
    __syncthreads();
    if (tid < 128) {
        int kz = tid >> 4, f = tid & 15;
        int tre = 2 * kz, tim = 2 * kz + 1;
        float Re = (ddsh[0][0][tre][f] + ddsh[1][0][tre][f])
                 + (ddsh[0][1][tim][f] + ddsh[1][1][tim][f]);
        float Im = (ddsh[0][0][tim][f] + ddsh[1][0][tim][f])
                 - (ddsh[0][1][tre][f] + ddsh[1][1][tre][f]);
        union { __bf16 h[2]; unsigned u; } pk;
        pk.h[0] = (__bf16)Re; pk.h[1] = (__bf16)Im;
        T2u[(size_t)((b * 32 + c) * 8 + kz) * 1024 + f * 64 + x] = pk.u;
    }
}

// MFMA 64->16 complex DFT (x-stage)
__global__ __launch_bounds__(256) void k_dftm(const __bf16* __restrict__ in,
                                              float2* __restrict__ outf,
                                              const __bf16* __restrict__ wy) {
    int rb = blockIdx.x * 16;
    __shared__ __bf16 af[32 * 72];                // 4608 B
    __shared__ float dd[2][2][16][18];            // 4608 B
    int tid = threadIdx.x, l = tid & 63, w = tid >> 6;
    {
        int r = tid >> 4, yq = tid & 15;
        bf16x8 v = *(const bf16x8*)(in + ((size_t)(rb + r) * 64 + yq * 4) * 2);
        bf16x4 re, im;
#pragma unroll
        for (int j = 0; j < 4; j++) { re[j] = v[2 * j]; im[j] = v[2 * j + 1]; }
        *(bf16x4*)&af[(2 * r) * 72 + yq * 4] = re;
        *(bf16x4*)&af[(2 * r + 1) * 72 + yq * 4] = im;
    }
    __syncthreads();
    int mt = w >> 1, nt = w & 1, col = l & 15, kg = l >> 4;
    f32x4 acc = (f32x4){0.f, 0.f, 0.f, 0.f};
#pragma unroll
    for (int kc = 0; kc < 2; kc++) {
        bf16x8 a = *(const bf16x8*)&af[(mt * 16 + col) * 72 + kc * 32 + kg * 8];
        const __bf16* wp = wy + (kc * 2 + nt) * 1024 + l * 8;
        bf16x8 bh = *(const bf16x8*)wp;
        bf16x8 blo = *(const bf16x8*)(wp + 512);
        acc = __builtin_amdgcn_mfma_f32_16x16x32_bf16(a, bh, acc, 0, 0, 0);
        acc = __builtin_amdgcn_mfma_f32_16x16x32_bf16(a, blo, acc, 0, 0, 0);
    }
#pragma unroll
    for (int r = 0; r < 4; r++) dd[mt][nt][kg * 4 + r][col] = acc[r];
    __syncthreads();
    {
        int cr = tid >> 4, f = tid & 15;
        int mt2 = cr >> 3, tre = (2 * cr) & 15, tim = (2 * cr + 1) & 15;
        float Re = dd[mt2][0][tre][f] + dd[mt2][1][tim][f];
        float Im = dd[mt2][0][tim][f] - dd[mt2][1][tre][f];
        int rg = rb + cr;
        outf[rg * 16 + f] = make_float2(Re, Im);
    }
}

// spectral multiply
__global__ __launch_bounds__(128) void k_specmul(const float2* __restrict__ Xf,
                                                 const float* __restrict__ swl,
                                                 float2* __restrict__ Yf) {
    int m = blockIdx.x;                           // 2048 = (kz,kyi,kxi)
    int kxi = m & 15, kyi = (m >> 4) & 15, kz = m >> 8;
    int corner = (kxi >= 8 ? 1 : 0) + (kyi >= 8 ? 2 : 0);
    int mx = kxi & 7, my = kyi & 7;
    __shared__ float2 wsd[1024];
    __shared__ float2 xfs[128];
    int tid = threadIdx.x;
    const float* wb = swl + (size_t)corner * 1048576 + mx * 128 + my * 16 + kz * 2;
    for (int idx = tid; idx < 1024; idx += 128) {
        int i = idx >> 5, o = idx & 31;
        const float* p = wb + (size_t)i * 32768 + o * 1024;
        wsd[idx] = make_float2(p[0], p[1]);
    }
    {
        int b = tid >> 5, i = tid & 31;
        xfs[tid] = Xf[(((b * 32 + i) * 8 + kz) * 16 + kyi) * 16 + kxi];
    }
    __syncthreads();
    int b = tid >> 5, o = tid & 31;
    float ar = 0.f, ai = 0.f;
#pragma unroll
    for (int i = 0; i < 32; i++) {
        float2 xv = xfs[b * 32 + i];
        float2 wv = wsd[i * 32 + o];
        ar += xv.x * wv.x - xv.y * wv.y;
        ai += xv.x * wv.y + xv.y * wv.x;
    }
    const float s = 1.0f / 262144.0f;
    Yf[(((b * 32 + o) * 8 + kz) * 16 + kyi) * 16 + kxi] = make_float2(ar * s, ai * s);
}

// inverse x: U1b[b][kz][x][kyi][o] (bf16 pairs) = sum_kx Yf * e^{+i}
__global__ __launch_bounds__(256) void k_xinv(const float2* __restrict__ Yf,
                                              unsigned* __restrict__ U1p) {
    int blk = blockIdx.x;                         // 1024 = (b,o,kz)
    int kz = blk & 7, o = (blk >> 3) & 31, b = blk >> 8;
    __shared__ float2 yfs[16][17];
    __shared__ float2 tw[64];
    int tid = threadIdx.x;
    if (tid < 64) { float s, c; sincosf(TW_STEP * tid, &s, &c); tw[tid] = make_float2(c, s); }
    {
        int kyi = tid >> 4, kxi = tid & 15;
        yfs[kyi][kxi] = Yf[(size_t)((b * 32 + o) * 8 + kz) * 256 + tid];
    }
    __syncthreads();
    size_t base = (size_t)((b * 8 + kz) * 64) * 512 + o;
#pragma unroll
    for (int r = 0; r < 4; r++) {
        int idx = tid + r * 256;
        int x = idx >> 4, kyi = idx & 15;
        float ar = 0.f, ai = 0.f;
#pragma unroll
        for (int kxi = 0; kxi < 16; kxi++) {
            int f = kxi < 8 ? kxi : kxi + 48;
            float2 t = tw[(f * x) & 63];
            float2 v = yfs[kyi][kxi];
            ar += v.x * t.x - v.y * t.y;
            ai += v.x * t.y + v.y * t.x;
        }
        union { __bf16 h[2]; unsigned u; } pk;
        pk.h[0] = (__bf16)ar; pk.h[1] = (__bf16)ai;
        U1p[base + (size_t)x * 512 + kyi * 32] = pk.u;
    }
}

// fused: P <- irfft_z(yinv(U1b)) + MFMA-pointwise(h) + cb ; emits bn partial sums.
// y-inverse uses conjugate-pair symmetry (freqs +-p share twiddles).
__global__ __launch_bounds__(256) void k_fuse(__bf16* __restrict__ P,
                                              const unsigned* __restrict__ U1p,
                                              const float* __restrict__ cwl,
                                              const float* __restrict__ cbl,
                                              const __bf16* __restrict__ wz,
                                              const float* __restrict__ bnp, int relu,
                                              float* __restrict__ part) {
    int blk = blockIdx.x;                         // 4096 = (yt,b,x)
    int yt = blk >> 8, bxi = blk & 255;
    int b = bxi >> 6, x = bxi & 63;
    int y0 = yt * 4;
    __shared__ __bf16 hs[256 * 40];               // 20480 B
    __shared__ __bf16 u2b[4][32][20];             // 5120 B: [yy][o][t], t = 0..15 (K-pad in regs)
    __shared__ float2 twl[64];                    // 512 B
    __shared__ float sredS[4][32], sredQ[4][32];  // 1024 B
    int tid = threadIdx.x;
    int l = tid & 63, w = tid >> 6;
    if (tid < 64) { float s, c; sincosf(TW_STEP * tid, &s, &c); twl[tid] = make_float2(c, s); }
    __syncthreads();

    int col = l & 15, kg = l >> 4;
    // cw fragments: cw[o][c], o = nt*16+col, c = kg*8+j
    bf16x8 cwf[2];
    float cbv[2];
#pragma unroll
    for (int nt = 0; nt < 2; nt++) {
        int o = nt * 16 + col;
        const float4* p4 = (const float4*)(cwl + o * 32 + kg * 8);
        float4 q0 = p4[0], q1 = p4[1];
        cwf[nt][0] = (__bf16)q0.x; cwf[nt][1] = (__bf16)q0.y;
        cwf[nt][2] = (__bf16)q0.z; cwf[nt][3] = (__bf16)q0.w;
        cwf[nt][4] = (__bf16)q1.x; cwf[nt][5] = (__bf16)q1.y;
        cwf[nt][6] = (__bf16)q1.z; cwf[nt][7] = (__bf16)q1.w;
        cbv[nt] = cbl[o];
    }

    // stage hs (bn+relu applied); jj-rotation to spread LDS banks
    {
        int c = tid >> 3, j = tid & 7;
        float scb = 1.f, shb = 0.f;
        if (bnp) { scb = bnp[c]; shb = bnp[32 + c]; }
        const __bf16* src = P + ((size_t)((b * 32 + c) * 64 + x) * 64 + y0) * 64 + j * 8;
#pragma unroll
        for (int q = 0; q < 4; q++) {
            bf16x8 v8 = *(const bf16x8*)(src + q * 64);
            float fv[8];
#pragma unroll
            for (int jj = 0; jj < 8; jj++) {
                float v = (float)v8[jj];
                if (bnp) { v = fmaf(v, scb, shb); if (relu) v = fmaxf(v, 0.f); }
                fv[jj] = v;
            }
#pragma unroll
            for (int s = 0; s < 8; s++) {
                int jr = (s + j) & 7;
                hs[(q * 64 + j * 8 + jr) * 40 + c] = (__bf16)fv[jr];
            }
        }
    }
    // stage u2b via y-inverse from bf16 U1, conjugate-pair symmetric
    {
        int o = tid & 31, kz = tid >> 5;          // 256 threads = 8 kz x 32 o
        const unsigned* u1p = U1p + (size_t)((b * 8 + kz) * 64 + x) * 512 + o;
        float ur[16], ui[16];
#pragma unroll
        for (int kyi = 0; kyi < 16; kyi++) {
            union { unsigned u; __bf16 h[2]; } pk;
            pk.u = u1p[kyi * 32];
            ur[kyi] = (float)pk.h[0]; ui[kyi] = (float)pk.h[1];
        }
        float spr[8], sdr[8], spi[8], sdi[8];
#pragma unroll
        for (int p = 1; p < 8; p++) {
            spr[p] = ur[p] + ur[16 - p]; sdr[p] = ur[p] - ur[16 - p];
            spi[p] = ui[p] + ui[16 - p]; sdi[p] = ui[p] - ui[16 - p];
        }
#pragma unroll
        for (int yy = 0; yy < 4; yy++) {
            int y = y0 + yy;
            float arv = ur[0], aiv = ui[0];
            float2 t8 = twl[(8 * y) & 63];        // f = -8: e^{-i 8 y step}
            arv = fmaf(ur[8], t8.x, arv); arv = fmaf(ui[8], t8.y, arv);
            aiv = fmaf(ui[8], t8.x, aiv); aiv = fmaf(-ur[8], t8.y, aiv);
#pragma unroll
            for (int p = 1; p < 8; p++) {
                float2 t = twl[(p * y) & 63];
                arv = fmaf(spr[p], t.x, arv); arv = fmaf(-sdi[p], t.y, arv);
                aiv = fmaf(spi[p], t.x, aiv); aiv = fmaf(sdr[p], t.y, aiv);
            }
            union { __bf16 h[2]; unsigned u; } pk;
            pk.h[0] = (__bf16)arv; pk.h[1] = (__bf16)aiv;
            *(unsigned*)&u2b[yy][o][2 * kz] = pk.u;
        }
    }
    __syncthreads();

    // MFMA pointwise: wave w owns y = y0+w (4 M-tiles of 16 z), 2 N-tiles of channels
    f32x4 acc[4][2];
#pragma unroll
    for (int i = 0; i < 4; i++) {
        bf16x8 a = *(const bf16x8*)&hs[((w * 4 + i) * 16 + col) * 40 + kg * 8];
#pragma unroll
        for (int nt = 0; nt < 2; nt++) {
            acc[i][nt] = (f32x4){0.f, 0.f, 0.f, 0.f};
            acc[i][nt] = __builtin_amdgcn_mfma_f32_16x16x32_bf16(a, cwf[nt], acc[i][nt], 0, 0, 0);
        }
    }
    // MFMA irfft-z: A = Wz (hi/lo), B = u2b (k>=16 zeros synthesized in regs)
    {
        bf16x8 u2f[2];
#pragma unroll
        for (int nt = 0; nt < 2; nt++) {
            bf16x8 v = (bf16x8){(__bf16)0.f, (__bf16)0.f, (__bf16)0.f, (__bf16)0.f,
                                (__bf16)0.f, (__bf16)0.f, (__bf16)0.f, (__bf16)0.f};
            if (kg < 2) {
                bf16x4 lo = *(const bf16x4*)&u2b[w][nt * 16 + col][kg * 8];
                bf16x4 hi = *(const bf16x4*)&u2b[w][nt * 16 + col][kg * 8 + 4];
                v[0] = lo[0]; v[1] = lo[1]; v[2] = lo[2]; v[3] = lo[3];
                v[4] = hi[0]; v[5] = hi[1]; v[6] = hi[2]; v[7] = hi[3];
            }
            u2f[nt] = v;
        }
#pragma unroll
        for (int i = 0; i < 4; i++) {
            int z = i * 16 + col;
            const __bf16* wp = wz + z * 32 + kg * 8;
            bf16x8 wzh = *(const bf16x8*)wp;
            bf16x8 wzl = *(const bf16x8*)(wp + 2048);
#pragma unroll
            for (int nt = 0; nt < 2; nt++) {
                acc[i][nt] = __builtin_amdgcn_mfma_f32_16x16x32_bf16(wzh, u2f[nt], acc[i][nt], 0, 0, 0);
                acc[i][nt] = __builtin_amdgcn_mfma_f32_16x16x32_bf16(wzl, u2f[nt], acc[i][nt], 0, 0, 0);
            }
        }
    }

    // store + stats
    float sacc[2] = {0.f, 0.f}, ssacc[2] = {0.f, 0.f};
#pragma unroll
    for (int nt = 0; nt < 2; nt++) {
        int o = nt * 16 + col;
        __bf16* dstb = P + ((size_t)((b * 32 + o) * 64 + x) * 64 + (y0 + w)) * 64;
#pragma unroll
        for (int i = 0; i < 4; i++) {
            int z0s = i * 16 + kg * 4;
            bf16x4 outv;
#pragma unroll
            for (int r = 0; r < 4; r++) {
                float f = acc[i][nt][r] + cbv[nt];
                sacc[nt] += f;
                ssacc[nt] = fmaf(f, f, ssacc[nt]);
                outv[r] = (__bf16)f;
            }
            *(bf16x4*)(dstb + z0s) = outv;
        }
    }
#pragma unroll
    for (int nt = 0; nt < 2; nt++) {
        sacc[nt] += __shfl_xor(sacc[nt], 16, 64);
        sacc[nt] += __shfl_xor(sacc[nt], 32, 64);
        ssacc[nt] += __shfl_xor(ssacc[nt], 16, 64);
        ssacc[nt] += __shfl_xor(ssacc[nt], 32, 64);
    }
    if (l < 16) {
        sredS[w][col] = sacc[0]; sredS[w][16 + col] = sacc[1];
        sredQ[w][col] = ssacc[0]; sredQ[w][16 + col] = ssacc[1];
    }
    __syncthreads();
    if (tid < 32) {
        float S = sredS[0][tid] + sredS[1][tid] + sredS[2][tid] + sredS[3][tid];
        float SS = sredQ[0][tid] + sredQ[1][tid] + sredQ[2][tid] + sredQ[3][tid];
        part[((size_t)tid * 4096 + blk) * 2 + 0] = S;
        part[((size_t)tid * 4096 + blk) * 2 + 1] = SS;
    }
}

// one block per channel: reduce 4096 partials -> bn scale/shift
__global__ __launch_bounds__(256) void k_red2(const float* __restrict__ part,
                                              const float* __restrict__ gamma,
                                              const float* __restrict__ beta,
                                              float* __restrict__ bnp) {
    int c = blockIdx.x;
    int tid = threadIdx.x;
    const float2* pc = (const float2*)(part + (size_t)c * 8192);
    float s = 0.f, ss = 0.f;
#pragma unroll
    for (int q = 0; q < 16; q++) { float2 v = pc[tid * 16 + q]; s += v.x; ss += v.y; }
#pragma unroll
    for (int d = 32; d; d >>= 1) { s += __shfl_down(s, d, 64); ss += __shfl_down(ss, d, 64); }
    __shared__ float ws[8];
    if ((tid & 63) == 0) { ws[(tid >> 6) * 2] = s; ws[(tid >> 6) * 2 + 1] = ss; }
    __syncthreads();
    if (tid == 0) {
        double S = (double)ws[0] + ws[2] + ws[4] + ws[6];
        double SS = (double)ws[1] + ws[3] + ws[5] + ws[7];
        const double invN = 1.0 / 1048576.0;
        double mean = S * invN;
        double var = SS * invN - mean * mean;
        float scl = gamma[c] * rsqrtf((float)var + 1e-5f);
        bnp[c] = scl;
        bnp[32 + c] = beta[c] - (float)mean * scl;
    }
}

// fold final bn into fc1
__global__ void k_prep(const float* __restrict__ w1, const float* __restrict__ b1,
                       const float* __restrict__ bnp,
                       __bf16* __restrict__ w1b, float* __restrict__ b1p) {
    int f = threadIdx.x;
    if (f >= 128) return;
    float acc = b1[f];
#pragma unroll
    for (int c = 0; c < 32; c++) {
        float wv = w1[f * 32 + c];
        w1b[f * 32 + c] = (__bf16)(wv * bnp[c]);
        acc = fmaf(wv, bnp[32 + c], acc);
    }
    b1p[f] = acc;
}

// head: fc1 (bn pre-folded, MFMA, D[f][vox]) + relu -> fc2 (row-reduce, 2 shfl).
__global__ __launch_bounds__(256) void k_head(const __bf16* __restrict__ P,
                                              const __bf16* __restrict__ w1b,
                                              const float* __restrict__ b1p,
                                              const float* __restrict__ w2,
                                              const float* __restrict__ b2,
                                              float* __restrict__ out) {
    __shared__ __bf16 hs[64 * 40];                // [vox][ch], stride 40
    int tid = threadIdx.x;
    int b = blockIdx.x >> 9;                      // 512 blocks per batch
    int r0 = (blockIdx.x & 511) * 512;            // 512 voxels per block
    int l = tid & 63;
    int w = tid >> 6;
    int col = l & 15, kg = l >> 4, hi = l >> 4;

    bf16x8 afr[8];
    f32x4 b1q[8], w2q[8];
    {
#pragma unroll
        for (int nt = 0; nt < 8; nt++) {
            afr[nt] = *(const bf16x8*)(w1b + (nt * 16 + col) * 32 + kg * 8);
            b1q[nt] = ((const f32x4*)b1p)[nt * 4 + hi];
            w2q[nt] = ((const f32x4*)w2)[nt * 4 + hi];
        }
    }
    float b2v = b2[0];
    int sc_c = tid & 31, sc_j = tid >> 5;
    const __bf16* srcb = P + (size_t)(b * 32 + sc_c) * 262144 + r0 + sc_j * 8;

    for (int t = 0; t < 8; t++) {
        {
            bf16x8 v8 = *(const bf16x8*)(srcb + t * 64);
#pragma unroll
            for (int s = 0; s < 8; s++) {
                int jr = (s + sc_j * 4) & 7;
                hs[(sc_j * 8 + jr) * 40 + sc_c] = v8[jr];
            }
        }
        __syncthreads();
        bf16x8 hfr = *(const bf16x8*)&hs[(w * 16 + col) * 40 + kg * 8];
        f32x4 acc[8];
#pragma unroll
        for (int nt = 0; nt < 8; nt++) {
            acc[nt] = (f32x4){0.f, 0.f, 0.f, 0.f};
            acc[nt] = __builtin_amdgcn_mfma_f32_16x16x32_bf16(afr[nt], hfr, acc[nt], 0, 0, 0);
        }
        float s = 0.f;
#pragma unroll
        for (int nt = 0; nt < 8; nt++) {
#pragma unroll
            for (int r = 0; r < 4; r++) {
                float val = fmaxf(acc[nt][r] + b1q[nt][r], 0.f);
                s = fmaf(w2q[nt][r], val, s);
            }
        }
        s += __shfl_xor(s, 16, 64);
        s += __shfl_xor(s, 32, 64);
        if (l < 16)
            out[b * 262144 + r0 + t * 64 + w * 16 + l] = s + b2v;
        __syncthreads();
    }
}

// ---------------- launcher ----------------
extern "C" void kernel_launch(void* const* d_in, const int* in_sizes, int n_in,
                              void* d_out, int out_size, void* d_ws, size_t ws_size,
                              hipStream_t stream) {
    const float* x     = (const float*)d_in[0];
    const float* fc0_w = (const float*)d_in[1];
    const float* fc0_b = (const float*)d_in[2];
    const float* sw    = (const float*)d_in[3];
    const float* cw    = (const float*)d_in[4];
    const float* cb    = (const float*)d_in[5];
    const float* gamma = (const float*)d_in[6];
    const float* beta  = (const float*)d_in[7];
    const float* fc1_w = (const float*)d_in[8];
    const float* fc1_b = (const float*)d_in[9];
    const float* fc2_w = (const float*)d_in[10];
    const float* fc2_b = (const float*)d_in[11];

    char* ws = (char*)d_ws;
    __bf16* P    = (__bf16*)(ws + OFF_P);
    __bf16* T2b  = (__bf16*)(ws + OFF_B2);
    unsigned* T2u = (unsigned*)(ws + OFF_B2);
    unsigned* U1p = (unsigned*)(ws + OFF_B2);
    float2* Xf   = (float2*)(ws + OFF_XF);
    float2* Yf   = (float2*)(ws + OFF_YF);
    float*  part = (float*)(ws + OFF_XF);
    float2* gtw  = (float2*)(ws + OFF_TW);
    float*  bnp  = (float*)(ws + OFF_BNP);
    __bf16* w1b  = (__bf16*)(ws + OFF_W1B);
    float*  b1p  = (float*)(ws + OFF_B1P);
    __bf16* wfz  = (__bf16*)(ws + OFF_WFZ);
    __bf16* wz   = (__bf16*)(ws + OFF_WZ);
    __bf16* wy   = (__bf16*)(ws + OFF_WY);

    k_twinit<<<1, 256, 0, stream>>>(gtw, wfz, wz, wy);
    k_lift<<<4096, 256, 0, stream>>>(x, fc0_w, fc0_b, P);

    for (int i = 0; i < 4; i++) {
        const float* bprev = (i == 0) ? nullptr : (bnp + (i - 1) * 64);
        int relu = (i > 0) ? 1 : 0;
        k_zfwd2<<<8192, 256, 0, stream>>>(P, wfz, wy, bprev, relu, T2u);
        k_dftm<<<1024, 256, 0, stream>>>(T2b, Xf, wy);
        k_specmul<<<2048, 128, 0, stream>>>(Xf, sw + (size_t)i * 4194304, Yf);
        k_xinv<<<1024, 256, 0, stream>>>(Yf, U1p);
        k_fuse<<<4096, 256, 0, stream>>>(P, U1p, cw + i * 1024, cb + i * 32, wz, bprev, relu, part);
        k_red2<<<32, 256, 0, stream>>>(part, gamma + i * 32, beta + i * 32, bnp + i * 64);
    }

    k_prep<<<1, 128, 0, stream>>>(fc1_w, fc1_b, bnp + 3 * 64, w1b, b1p);
    k_head<<<2048, 256, 0, stream>>>(P, w1b, b1p, fc2_w, fc2_b, (float*)d_out);
}